// Round 1
// baseline (394.048 us; speedup 1.0000x reference)
//
#include <hip/hip_runtime.h>
#include <hip/hip_bf16.h>
#include <math.h>

// ---------------------------------------------------------------------------
// PatentCitationMoEModule — MI355X implementation
//
// Pipeline (all on `stream`, no sync, graph-capture safe):
//  1. prep_kq      : kq = Wk @ (gc@Wq + bq), qbk = q.bk       (32 blocks)
//  2. transpose_conv x3 : W{1,2,3} fp32 [E][K][N] -> bf16 [E][N][K]
//  3. router_kernel: embeddings -> scores(GEMV) -> softmax -> xbar ->
//                    pooled=xbar@Wv -> LN -> gate -> top2 (+idx to d_out)
//  4. pack_kernel  : compact (token,expert) assignments by expert
//  5. gather_bib   : gather bib rows to compact bf16 X [4096][512]
//  6. expert_gemm x3 : m97-style 128x128 bf16 MFMA GEMM per expert segment
//  7. head_kernel  : logits = (gw0*O[a0]+gw1*O[a1]) @ head_W + head_b
// ---------------------------------------------------------------------------

#define LN_EPS 1e-5f

typedef __bf16 bf16_t;
typedef __bf16 bf16x8 __attribute__((ext_vector_type(8)));
typedef float f32x4 __attribute__((ext_vector_type(4)));

__device__ __forceinline__ void async_ld16(const void* g, void* l) {
  __builtin_amdgcn_global_load_lds(
      (__attribute__((address_space(1))) void*)g,
      (__attribute__((address_space(3))) void*)l, 16, 0, 0);
}

// --------------------------- prep: kq vector -------------------------------
__global__ __launch_bounds__(256)
void prep_kq(const float* __restrict__ Wq, const float* __restrict__ bq,
             const float* __restrict__ Wk, const float* __restrict__ bk,
             const float* __restrict__ gc, float* __restrict__ kq_out) {
  __shared__ float q[256];
  __shared__ float red[4];
  const int t = threadIdx.x, bi = blockIdx.x;
  float s = bq[t];
  for (int d = 0; d < 256; d++) s += gc[d] * Wq[d * 256 + t];
  q[t] = s;
  __syncthreads();
  const int rl = t >> 5, sl = t & 31;
  const int r = bi * 8 + rl;
  float p = 0.f;
#pragma unroll
  for (int i = 0; i < 8; i++) { const int d = sl + 32 * i; p += Wk[r * 256 + d] * q[d]; }
#pragma unroll
  for (int o = 16; o > 0; o >>= 1) p += __shfl_down(p, o, 32);
  if (sl == 0) kq_out[r] = p;
  if (bi == 0) {
    float z = q[t] * bk[t];
    const int lane = t & 63, wave = t >> 6;
#pragma unroll
    for (int o = 32; o > 0; o >>= 1) z += __shfl_down(z, o);
    if (lane == 0) red[wave] = z;
    __syncthreads();
    if (t == 0) kq_out[256] = red[0] + red[1] + red[2] + red[3];
  }
}

// ------------------- weight transpose + fp32->bf16 -------------------------
// W [E][R][C] fp32  ->  Wt [E][C][R] bf16
__global__ __launch_bounds__(256)
void transpose_conv(const float* __restrict__ W, bf16_t* __restrict__ Wt,
                    int R, int C) {
  __shared__ float tile[32][33];
  const int e = blockIdx.z;
  const int c0 = blockIdx.x * 32, r0 = blockIdx.y * 32;
  const int tx = threadIdx.x & 31, ty = threadIdx.x >> 5;
  const float* Wp = W + (size_t)e * R * C;
  bf16_t* Wtp = Wt + (size_t)e * R * C;
#pragma unroll
  for (int i = 0; i < 4; i++)
    tile[ty + 8 * i][tx] = Wp[(size_t)(r0 + ty + 8 * i) * C + (c0 + tx)];
  __syncthreads();
#pragma unroll
  for (int i = 0; i < 4; i++)
    Wtp[(size_t)(c0 + ty + 8 * i) * R + (r0 + tx)] = (bf16_t)tile[tx][ty + 8 * i];
}

// ------------------------------ router -------------------------------------
__global__ __launch_bounds__(256)
void router_kernel(const int* __restrict__ ipc_idx, const int* __restrict__ role_idx,
                   const int* __restrict__ maskp,
                   const float* __restrict__ ipc_emb, const float* __restrict__ role_emb,
                   const float* __restrict__ kq_qbk,
                   const float* __restrict__ Wv, const float* __restrict__ bvec,
                   const float* __restrict__ ln_g, const float* __restrict__ ln_b,
                   const float* __restrict__ gate_W, const float* __restrict__ gate_b,
                   const float* __restrict__ expert_biases,
                   float* __restrict__ out_idx_f, int* __restrict__ ws_idx,
                   float* __restrict__ ws_gw) {
  const int b = blockIdx.x;
  __shared__ float sc[64];
  __shared__ float attn_s[64];
  __shared__ __align__(16) float part[4][256];
  __shared__ float xbar[256];
  __shared__ float rv[256];
  __shared__ float red[4];
  __shared__ float aff[8];
  const int t = threadIdx.x, wave = t >> 6, lane = t & 63;
  const int d0 = lane * 4;
  const float4 kq = *(const float4*)(kq_qbk + d0);
  const float qbk = kq_qbk[256];

  // phase 1: scores[l] = x[l] . kq + qbk  (masked)
  for (int l = wave; l < 64; l += 4) {
    const int ii = ipc_idx[b * 64 + l], ri = role_idx[b * 64 + l];
    const float4 xe = *(const float4*)(ipc_emb + (size_t)ii * 256 + d0);
    const float4 re = *(const float4*)(role_emb + (size_t)ri * 256 + d0);
    float p = (xe.x + re.x) * kq.x + (xe.y + re.y) * kq.y +
              (xe.z + re.z) * kq.z + (xe.w + re.w) * kq.w;
#pragma unroll
    for (int o = 32; o > 0; o >>= 1) p += __shfl_down(p, o);
    if (lane == 0) sc[l] = (maskp[b * 64 + l] == 0) ? -1e9f : (p + qbk);
  }
  __syncthreads();
  // phase 2: softmax over 64 (wave 0)
  if (wave == 0) {
    const float s = sc[lane];
    float m = s;
#pragma unroll
    for (int o = 32; o > 0; o >>= 1) m = fmaxf(m, __shfl_xor(m, o));
    const float ev = expf(s - m);
    float sum = ev;
#pragma unroll
    for (int o = 32; o > 0; o >>= 1) sum += __shfl_xor(sum, o);
    attn_s[lane] = ev / sum;
  }
  __syncthreads();
  // phase 3: xbar[d] = sum_l attn[l] * x[l][d] (re-gather, L2-hot)
  float p0 = 0.f, p1 = 0.f, p2 = 0.f, p3 = 0.f;
  for (int l = wave; l < 64; l += 4) {
    const float a = attn_s[l];
    const int ii = ipc_idx[b * 64 + l], ri = role_idx[b * 64 + l];
    const float4 xe = *(const float4*)(ipc_emb + (size_t)ii * 256 + d0);
    const float4 re = *(const float4*)(role_emb + (size_t)ri * 256 + d0);
    p0 += a * (xe.x + re.x); p1 += a * (xe.y + re.y);
    p2 += a * (xe.z + re.z); p3 += a * (xe.w + re.w);
  }
  *(float4*)&part[wave][d0] = make_float4(p0, p1, p2, p3);
  __syncthreads();
  xbar[t] = part[0][t] + part[1][t] + part[2][t] + part[3][t];
  __syncthreads();
  // phase 4: pooled[t] = xbar . Wv[:,t] + bv[t]
  float pv = bvec[t];
  for (int d = 0; d < 256; d++) pv += xbar[d] * Wv[d * 256 + t];
  // layernorm (two-pass, fp32)
  float s1 = pv;
#pragma unroll
  for (int o = 32; o > 0; o >>= 1) s1 += __shfl_down(s1, o);
  if (lane == 0) red[wave] = s1;
  __syncthreads();
  const float mu = (red[0] + red[1] + red[2] + red[3]) * (1.f / 256.f);
  __syncthreads();
  const float df = pv - mu;
  float s2 = df * df;
#pragma unroll
  for (int o = 32; o > 0; o >>= 1) s2 += __shfl_down(s2, o);
  if (lane == 0) red[wave] = s2;
  __syncthreads();
  const float var = (red[0] + red[1] + red[2] + red[3]) * (1.f / 256.f);
  rv[t] = df / sqrtf(var + LN_EPS) * ln_g[t] + ln_b[t];
  __syncthreads();
  // gate: affinity[j] = rv . gate_W[:,j] + gate_b[j]  (wave 0)
  if (wave == 0) {
    const int j = lane & 7, dbase = (lane >> 3) * 32;
    float p = 0.f;
    for (int i = 0; i < 32; i++) p += rv[dbase + i] * gate_W[(dbase + i) * 8 + j];
    p += __shfl_xor(p, 8); p += __shfl_xor(p, 16); p += __shfl_xor(p, 32);
    if (lane < 8) aff[j] = p + gate_b[j];
  }
  __syncthreads();
  // top-2 (selection on affinity+bias, weights on raw affinity)
  if (t == 0) {
    float b0 = -1e30f; int i0 = 0;
    for (int j = 0; j < 8; j++) {
      const float s = aff[j] + expert_biases[j];
      if (s > b0) { b0 = s; i0 = j; }
    }
    float b1v = -1e30f; int i1 = 0;
    for (int j = 0; j < 8; j++) {
      if (j == i0) continue;
      const float s = aff[j] + expert_biases[j];
      if (s > b1v) { b1v = s; i1 = j; }
    }
    const float a0 = aff[i0], a1 = aff[i1];
    const float m = fmaxf(a0, a1);
    const float e0 = expf(a0 - m), e1 = expf(a1 - m);
    const float inv = 1.f / (e0 + e1);
    ws_idx[b * 2] = i0; ws_idx[b * 2 + 1] = i1;
    ws_gw[b * 2] = e0 * inv; ws_gw[b * 2 + 1] = e1 * inv;
    out_idx_f[b * 2] = (float)i0; out_idx_f[b * 2 + 1] = (float)i1;
  }
}

// ------------------------------ pack ---------------------------------------
__global__ __launch_bounds__(256)
void pack_kernel(const int* __restrict__ ws_idx, int* __restrict__ list_token,
                 int* __restrict__ a_of, int* __restrict__ offsets_g) {
  __shared__ int cnt[8]; __shared__ int off[9]; __shared__ int fill[8];
  const int t = threadIdx.x;
  if (t < 8) cnt[t] = 0;
  __syncthreads();
  for (int a = t; a < 4096; a += 256) atomicAdd(&cnt[ws_idx[a]], 1);
  __syncthreads();
  if (t == 0) { off[0] = 0; for (int e = 0; e < 8; e++) off[e + 1] = off[e] + cnt[e]; }
  __syncthreads();
  if (t < 8) fill[t] = off[t];
  if (t < 9) offsets_g[t] = off[t];
  __syncthreads();
  for (int a = t; a < 4096; a += 256) {
    const int e = ws_idx[a];
    const int pos = atomicAdd(&fill[e], 1);
    list_token[pos] = a >> 1;
    a_of[a] = pos;
  }
}

// --------------------------- gather bib -> bf16 ----------------------------
__global__ __launch_bounds__(64)
void gather_bib(const float* __restrict__ bib, const int* __restrict__ list_token,
                bf16_t* __restrict__ Xc) {
  const int a = blockIdx.x;
  const int tok = list_token[a];
  const int t = threadIdx.x;
  const float4 v1 = *(const float4*)(bib + (size_t)tok * 512 + t * 8);
  const float4 v2 = *(const float4*)(bib + (size_t)tok * 512 + t * 8 + 4);
  bf16x8 o;
  o[0] = (bf16_t)v1.x; o[1] = (bf16_t)v1.y; o[2] = (bf16_t)v1.z; o[3] = (bf16_t)v1.w;
  o[4] = (bf16_t)v2.x; o[5] = (bf16_t)v2.y; o[6] = (bf16_t)v2.z; o[7] = (bf16_t)v2.w;
  *(bf16x8*)(Xc + (size_t)a * 512 + t * 8) = o;
}

// --------------------- expert GEMM (m97 structure) --------------------------
// C[rows, N] = A[rows, K] @ B  where Bt = B^T [E][N][K]; rows segmented by expert.
template <bool RELU, typename OUT_T>
__global__ __launch_bounds__(256)
void expert_gemm(const bf16_t* __restrict__ A, const bf16_t* __restrict__ Bt,
                 const float* __restrict__ bias, OUT_T* __restrict__ C,
                 const int* __restrict__ offsets, int K, int N) {
  const int e = blockIdx.z;
  const int seg_hi = offsets[e + 1];
  const int row0 = offsets[e] + blockIdx.y * 128;
  if (row0 >= seg_hi) return;
  const int n0 = blockIdx.x * 128;
  __shared__ __align__(16) bf16_t As[128 * 32];
  __shared__ __align__(16) bf16_t Bs[128 * 32];
  const int t = threadIdx.x;
  const int wave = t >> 6, lane = t & 63;
  const int wm = wave >> 1, wn = wave & 1;
  const bf16_t* Ab = A + (size_t)row0 * K;
  const bf16_t* Bb = Bt + ((size_t)e * N + n0) * K;
  const int r0s = (wave * 2 + 0) * 16 + (lane >> 2);
  const int r1s = (wave * 2 + 1) * 16 + (lane >> 2);
  const int kg = (lane & 3) * 8;
  bf16_t* la0 = As + (wave * 2 + 0) * 512 + lane * 8;
  bf16_t* la1 = As + (wave * 2 + 1) * 512 + lane * 8;
  bf16_t* lb0 = Bs + (wave * 2 + 0) * 512 + lane * 8;
  bf16_t* lb1 = Bs + (wave * 2 + 1) * 512 + lane * 8;
  f32x4 acc[4][4];
#pragma unroll
  for (int i = 0; i < 4; i++)
#pragma unroll
    for (int j = 0; j < 4; j++) acc[i][j] = (f32x4){0.f, 0.f, 0.f, 0.f};
  const int fr = lane & 15, fq = (lane >> 4) * 8;
  for (int kk = 0; kk < K; kk += 32) {
    async_ld16(Ab + (size_t)r0s * K + kk + kg, la0);
    async_ld16(Ab + (size_t)r1s * K + kk + kg, la1);
    async_ld16(Bb + (size_t)r0s * K + kk + kg, lb0);
    async_ld16(Bb + (size_t)r1s * K + kk + kg, lb1);
    __syncthreads();
    bf16x8 af[4], bfv[4];
#pragma unroll
    for (int mi = 0; mi < 4; mi++)
      af[mi] = *(const bf16x8*)(As + (wm * 64 + mi * 16 + fr) * 32 + fq);
#pragma unroll
    for (int ni = 0; ni < 4; ni++)
      bfv[ni] = *(const bf16x8*)(Bs + (wn * 64 + ni * 16 + fr) * 32 + fq);
    __syncthreads();
#pragma unroll
    for (int mi = 0; mi < 4; mi++)
#pragma unroll
      for (int ni = 0; ni < 4; ni++)
        acc[mi][ni] = __builtin_amdgcn_mfma_f32_16x16x32_bf16(af[mi], bfv[ni], acc[mi][ni], 0, 0, 0);
  }
  // epilogue: C/D layout row=(lane>>4)*4+r, col=lane&15  [m89/m91 verified]
#pragma unroll
  for (int ni = 0; ni < 4; ni++) {
    const int col = n0 + wn * 64 + ni * 16 + fr;
    const float bv = bias[e * N + col];
#pragma unroll
    for (int mi = 0; mi < 4; mi++) {
#pragma unroll
      for (int r = 0; r < 4; r++) {
        const int grow = row0 + wm * 64 + mi * 16 + (lane >> 4) * 4 + r;
        if (grow < seg_hi) {
          float v = acc[mi][ni][r] + bv;
          if (RELU) v = fmaxf(v, 0.f);
          C[(size_t)grow * N + col] = (OUT_T)v;
        }
      }
    }
  }
}

// ------------------------------ head ---------------------------------------
__global__ __launch_bounds__(256)
void head_kernel(const float* __restrict__ O, const int* __restrict__ a_of,
                 const float* __restrict__ ws_gw, const float* __restrict__ head_W,
                 const float* __restrict__ head_b, float* __restrict__ out) {
  const int b = blockIdx.x, t = threadIdx.x;
  __shared__ float m[512];
  const int a0 = a_of[b * 2], a1 = a_of[b * 2 + 1];
  const float g0 = ws_gw[b * 2], g1 = ws_gw[b * 2 + 1];
  for (int d = t; d < 512; d += 256)
    m[d] = g0 * O[(size_t)a0 * 512 + d] + g1 * O[(size_t)a1 * 512 + d];
  __syncthreads();
  if (t < 160) {
    const int c = t >> 4, ch = t & 15;
    float p = 0.f;
#pragma unroll
    for (int i = 0; i < 32; i++) {
      const int d = i * 16 + ch;  // bank-friendly stride
      p += m[d] * head_W[d * 10 + c];
    }
#pragma unroll
    for (int o = 8; o > 0; o >>= 1) p += __shfl_down(p, o, 16);
    if (ch == 0) out[b * 10 + c] = p + head_b[c];
  }
}

// ------------------------------ launch --------------------------------------
extern "C" void kernel_launch(void* const* d_in, const int* in_sizes, int n_in,
                              void* d_out, int out_size, void* d_ws, size_t ws_size,
                              hipStream_t stream) {
  const int* ipc_idx = (const int*)d_in[0];
  const int* role_idx = (const int*)d_in[1];
  const float* bib = (const float*)d_in[2];
  const int* maskp = (const int*)d_in[3];
  // d_in[4] = top_k (always 2)
  const float* ipc_emb = (const float*)d_in[5];
  const float* role_emb = (const float*)d_in[6];
  const float* Wq = (const float*)d_in[7];
  const float* bq = (const float*)d_in[8];
  const float* Wk = (const float*)d_in[9];
  const float* bk = (const float*)d_in[10];
  const float* Wv = (const float*)d_in[11];
  const float* bv = (const float*)d_in[12];
  const float* gc = (const float*)d_in[13];
  const float* ln_g = (const float*)d_in[14];
  const float* ln_b = (const float*)d_in[15];
  const float* gate_W = (const float*)d_in[16];
  const float* gate_b = (const float*)d_in[17];
  const float* exp_b = (const float*)d_in[18];
  const float* W1 = (const float*)d_in[19];
  const float* b1 = (const float*)d_in[20];
  const float* W2 = (const float*)d_in[21];
  const float* b2 = (const float*)d_in[22];
  const float* W3 = (const float*)d_in[23];
  const float* b3 = (const float*)d_in[24];
  const float* head_W = (const float*)d_in[25];
  const float* head_b = (const float*)d_in[26];

  char* ws = (char*)d_ws;
  size_t off = 0;
  auto alloc = [&](size_t bytes) -> char* {
    char* p = ws + off;
    off += (bytes + 255) & ~(size_t)255;
    return p;
  };
  float* kq_qbk = (float*)alloc(257 * 4);
  int* ws_idx = (int*)alloc(4096 * 4);
  float* ws_gw = (float*)alloc(4096 * 4);
  int* list_tok = (int*)alloc(4096 * 4);
  int* a_of = (int*)alloc(4096 * 4);
  int* offs = (int*)alloc(9 * 4);
  bf16_t* W1t = (bf16_t*)alloc((size_t)8 * 1024 * 512 * 2);
  bf16_t* W2t = (bf16_t*)alloc((size_t)8 * 1024 * 1024 * 2);
  bf16_t* W3t = (bf16_t*)alloc((size_t)8 * 512 * 1024 * 2);
  bf16_t* Xc = (bf16_t*)alloc((size_t)4224 * 512 * 2);   // +128 pad rows (poison-safe)
  bf16_t* H1c = (bf16_t*)alloc((size_t)4224 * 1024 * 2);
  bf16_t* H2c = (bf16_t*)alloc((size_t)4224 * 1024 * 2);
  float* Oc = (float*)alloc((size_t)4224 * 512 * 4);
  (void)in_sizes; (void)n_in; (void)out_size; (void)ws_size;

  float* out_logits = (float*)d_out;          // [2048*10]
  float* out_idx = (float*)d_out + 20480;     // [2048*2] as float

  prep_kq<<<32, 256, 0, stream>>>(Wq, bq, Wk, bk, gc, kq_qbk);
  transpose_conv<<<dim3(1024 / 32, 512 / 32, 8), 256, 0, stream>>>(W1, W1t, 512, 1024);
  transpose_conv<<<dim3(1024 / 32, 1024 / 32, 8), 256, 0, stream>>>(W2, W2t, 1024, 1024);
  transpose_conv<<<dim3(512 / 32, 1024 / 32, 8), 256, 0, stream>>>(W3, W3t, 1024, 512);
  router_kernel<<<2048, 256, 0, stream>>>(ipc_idx, role_idx, maskp, ipc_emb, role_emb,
                                          kq_qbk, Wv, bv, ln_g, ln_b, gate_W, gate_b,
                                          exp_b, out_idx, ws_idx, ws_gw);
  pack_kernel<<<1, 256, 0, stream>>>(ws_idx, list_tok, a_of, offs);
  gather_bib<<<4096, 64, 0, stream>>>(bib, list_tok, Xc);
  expert_gemm<true, bf16_t><<<dim3(8, 16, 8), 256, 0, stream>>>(Xc, W1t, b1, H1c, offs, 512, 1024);
  expert_gemm<true, bf16_t><<<dim3(8, 16, 8), 256, 0, stream>>>(H1c, W2t, b2, H2c, offs, 1024, 1024);
  expert_gemm<false, float><<<dim3(4, 16, 8), 256, 0, stream>>>(H2c, W3t, b3, Oc, offs, 1024, 512);
  head_kernel<<<2048, 256, 0, stream>>>(Oc, a_of, ws_gw, head_W, head_b, out_logits);
}